// Round 5
// baseline (147.642 us; speedup 1.0000x reference)
//
#include <hip/hip_runtime.h>

typedef __bf16 bf16_t;
typedef __attribute__((ext_vector_type(8))) __bf16 bf16x8;
typedef __attribute__((ext_vector_type(4))) __bf16 bf16x4;
typedef __attribute__((ext_vector_type(4))) float f32x4;

// LDS layout (bytes), 39424 total (rounds to 40960 w/ runtime 256 at 8KB granule
// -> 4 blocks/CU by LDS; 3 if granule coarser):
//   Xw [49 rows][256B] at [0,12544)     } live: stage -> V-proj
//   Q  [49 rows][256B] at [12544,25088) } live: QK-proj -> QK^T
//   K  [49 rows][256B] at [25088,37632) } live: QK-proj -> QK^T
//   Vt [128 rows][112B] at [25088,39424)  <- overlays K after barrier B (V-proj deferred)
//   P  [49 rows][512B] at [0,25088)       <- overlays Xw+Q after barrier C
//   O  [64 rows][256B] at [0,16384)       <- overlays P after barrier D
// Rows >=49 of Xw/Q/K/P never stored; reads clamp row->48 (garbage masked by
// bias=-1e4 on keys n>=49 and the m<49 output-store guard).
#define LDS_XW 0
#define LDS_Q  12544
#define LDS_K  25088
#define LDS_VT 25088
#define LDS_P  0
#define LDS_O  0

// ws layout (bf16 elements): wq_pack[16384] wk_pack[16384] wv_pack[16384] wo_pack[16384]
// biasPad[8*64*64]  => 98304 elements = 196608 bytes

__device__ __forceinline__ bf16x8 zero8() {
    bf16x8 v;
#pragma unroll
    for (int i = 0; i < 8; ++i) v[i] = (bf16_t)0.0f;
    return v;
}

__global__ void repack_kernel(const float* __restrict__ wq, const float* __restrict__ wk,
                              const float* __restrict__ wv, const float* __restrict__ wo,
                              const float* __restrict__ rel_bias, bf16_t* __restrict__ ws)
{
    int idx = blockIdx.x * 256 + threadIdx.x;
    if (idx < 65536) {
        // B-fragment order for mfma_f32_16x16x32_bf16:
        // pack[(((ks*8 + nt)*64 + lane)*8 + j)] = W[ks*32 + (lane>>4)*8 + j][nt*16 + (lane&15)]
        int mat = idx >> 14;
        int r = idx & 16383;
        int j = r & 7, l = (r >> 3) & 63, nt = (r >> 9) & 7, ks = r >> 12;
        int k = ks * 32 + (l >> 4) * 8 + j;
        int n = nt * 16 + (l & 15);
        const float* w = (mat == 0) ? wq : (mat == 1) ? wk : (mat == 2) ? wv : wo;
        float v = w[k * 128 + n];
        if (mat == 0) v *= 0.25f;            // fold q scale HS^-0.5
        ws[idx] = (bf16_t)v;
    } else if (idx < 98304) {
        // biasPad[h][m][n], padding (m>=49 or n>=49) = -1e4 (doubles as softmax mask)
        int r = idx - 65536;
        int h = r >> 12, m = (r >> 6) & 63, n = r & 63;
        float v = -10000.0f;
        if (m < 49 && n < 49) {
            int im = m / 7, jm = m % 7, in_ = n / 7, jn = n % 7;
            v = rel_bias[((im - in_ + 6) * 13 + (jm - jn + 6)) * 8 + h];
        }
        ws[idx] = (bf16_t)v;
    }
}

__global__ __launch_bounds__(256, 2)
void win_attn_kernel(const float* __restrict__ x, const float* __restrict__ b_o,
                     const bf16_t* __restrict__ wpack, float* __restrict__ out)
{
    __shared__ __align__(16) unsigned char smem[39424];
    const bf16_t* biasT = wpack + 65536;
    const int tid = threadIdx.x;
    const int blk = blockIdx.x;                  // 4096 windows: b*256 + wh*16 + ww
    const int b  = blk >> 8;
    const int wh = (blk >> 4) & 15;
    const int ww = blk & 15;
    const int wv = tid >> 6;                     // wave 0..3, owns heads {2wv,2wv+1}, cols [32wv,32wv+32)
    const int lane = tid & 63;
    const int c  = lane & 15;
    const int hi = lane >> 4;                    // 0..3
    const f32x4 fzero = {0.f, 0.f, 0.f, 0.f};

    // ---------------- stage x window -> Xw [49][128] bf16 ----------------
#pragma unroll
    for (int it = 0; it < 7; ++it) {
        int idx = tid + it * 256;                // need 1568 = 49 rows * 32 float4
        if (idx < 1568) {
            int m  = idx >> 5;                   // 0..48
            int c4 = idx & 31;
            int i = m / 7, j = m - 7 * i;
            float4 v = *(const float4*)(x + ((b * 112 + wh * 7 + i) * 112 + ww * 7 + j) * 128 + c4 * 4);
            bf16x4 bv;
            bv[0] = (bf16_t)v.x; bv[1] = (bf16_t)v.y; bv[2] = (bf16_t)v.z; bv[3] = (bf16_t)v.w;
            int ch = (c4 >> 1) ^ (m & 7);        // 16B-chunk XOR swizzle
            *(bf16x4*)(smem + LDS_XW + m * 256 + ch * 16 + (c4 & 1) * 8) = bv;
        }
    }
    __syncthreads();                             // barrier A: Xw ready

    // ---------------- Q, K projections (row-major, wave-private columns) ----------------
#pragma unroll
    for (int mat = 0; mat < 2; ++mat) {
        bf16x8 bw[4][2];
#pragma unroll
        for (int ks = 0; ks < 4; ++ks)
#pragma unroll
            for (int ntl = 0; ntl < 2; ++ntl)
                bw[ks][ntl] = *(const bf16x8*)(wpack + mat * 16384 +
                                 ((ks * 8 + (2 * wv + ntl)) * 64 + lane) * 8);
#pragma unroll
        for (int mt = 0; mt < 4; ++mt) {
            int row = mt * 16 + c;
            int rowc = (row < 49) ? row : 48;    // clamp: rows >=49 read row 48 (finite dup)
            bf16x8 a[4];
#pragma unroll
            for (int ks = 0; ks < 4; ++ks) {
                int ch = (4 * ks + hi) ^ (rowc & 7);
                a[ks] = *(const bf16x8*)(smem + LDS_XW + rowc * 256 + ch * 16);
            }
            f32x4 acc[2] = {fzero, fzero};
#pragma unroll
            for (int ks = 0; ks < 4; ++ks)
#pragma unroll
                for (int ntl = 0; ntl < 2; ++ntl)
                    acc[ntl] = __builtin_amdgcn_mfma_f32_16x16x32_bf16(a[ks], bw[ks][ntl], acc[ntl], 0, 0, 0);
            // C layout: col = lane&15, row = 4*hi + reg
#pragma unroll
            for (int ntl = 0; ntl < 2; ++ntl)
#pragma unroll
                for (int r = 0; r < 4; ++r) {
                    int orow = mt * 16 + hi * 4 + r;
                    if (orow < 49) {
                        int col = 32 * wv + ntl * 16 + c;
                        int ch = (col >> 3) ^ (orow & 7);
                        *(bf16_t*)(smem + (mat == 0 ? LDS_Q : LDS_K) + orow * 256 + ch * 16 + (col & 7) * 2)
                            = (bf16_t)acc[ntl][r];
                    }
                }
        }
    }
    // no barrier: each wave's QK^T reads only its own 32 channel-columns of Q/K

    // ---------------- S^T = K·Q^T (+bias) -> softmax over n -> pack P in regs ----------------
    bf16x4 pk[2][16];
#pragma unroll
    for (int hl = 0; hl < 2; ++hl) {
        int h = 2 * wv + hl;
        bf16x8 ka[4];
#pragma unroll
        for (int t = 0; t < 4; ++t) {
            int row = t * 16 + c;
            int rowc = (row < 49) ? row : 48;
            if (hi < 2) {                        // HS=16: k=16..31 lanes supply zeros
                int ch = (4 * wv + 2 * hl + hi) ^ (rowc & 7);
                ka[t] = *(const bf16x8*)(smem + LDS_K + rowc * 256 + ch * 16);
            } else {
                ka[t] = zero8();
            }
        }
#pragma unroll
        for (int mt = 0; mt < 4; ++mt) {         // per-mt: only st[4] live (low VGPR)
            int row = mt * 16 + c;
            int rowc = (row < 49) ? row : 48;
            bf16x8 qb;
            if (hi < 2) {
                int ch = (4 * wv + 2 * hl + hi) ^ (rowc & 7);
                qb = *(const bf16x8*)(smem + LDS_Q + rowc * 256 + ch * 16);
            } else {
                qb = zero8();
            }
            f32x4 st[4];                         // S^T slice; col=m=c, row=n=nt*16+4hi+r
#pragma unroll
            for (int nt = 0; nt < 4; ++nt)
                st[nt] = __builtin_amdgcn_mfma_f32_16x16x32_bf16(ka[nt], qb, fzero, 0, 0, 0);
#pragma unroll
            for (int nt = 0; nt < 4; ++nt) {
                int m = mt * 16 + c;
                bf16x4 bb = *(const bf16x4*)(biasT + (h * 64 + m) * 64 + nt * 16 + 4 * hi);
#pragma unroll
                for (int r = 0; r < 4; ++r)
                    st[nt][r] += (float)bb[r];
            }
            float mx = -3.0e30f;
#pragma unroll
            for (int nt = 0; nt < 4; ++nt)
#pragma unroll
                for (int r = 0; r < 4; ++r) mx = fmaxf(mx, st[nt][r]);
            mx = fmaxf(mx, __shfl_xor(mx, 16));
            mx = fmaxf(mx, __shfl_xor(mx, 32));
            float sum = 0.f;
#pragma unroll
            for (int nt = 0; nt < 4; ++nt)
#pragma unroll
                for (int r = 0; r < 4; ++r) {
                    float p = __expf(st[nt][r] - mx);
                    st[nt][r] = p;
                    sum += p;
                }
            sum += __shfl_xor(sum, 16);
            sum += __shfl_xor(sum, 32);
            float inv = 1.f / sum;
#pragma unroll
            for (int nt = 0; nt < 4; ++nt) {
                bf16x4 pv;
#pragma unroll
                for (int r = 0; r < 4; ++r) pv[r] = (bf16_t)(st[nt][r] * inv);
                pk[hl][nt * 4 + mt] = pv;
            }
        }
    }
    __syncthreads();                             // barrier B: all Q/K reads done -> Vt may clobber K

    // ---------------- V projection (deferred): read Xw, write Vt over K region ----------------
    {
        f32x4 vacc[4][2];
#pragma unroll
        for (int mt = 0; mt < 4; ++mt) { vacc[mt][0] = fzero; vacc[mt][1] = fzero; }
#pragma unroll
        for (int ks = 0; ks < 4; ++ks) {
            bf16x8 bw0 = *(const bf16x8*)(wpack + 2 * 16384 + ((ks * 8 + 2 * wv) * 64 + lane) * 8);
            bf16x8 bw1 = *(const bf16x8*)(wpack + 2 * 16384 + ((ks * 8 + 2 * wv + 1) * 64 + lane) * 8);
#pragma unroll
            for (int mt = 0; mt < 4; ++mt) {
                int row = mt * 16 + c;
                int rowc = (row < 49) ? row : 48;
                int ch = (4 * ks + hi) ^ (rowc & 7);
                bf16x8 a = *(const bf16x8*)(smem + LDS_XW + rowc * 256 + ch * 16);
                vacc[mt][0] = __builtin_amdgcn_mfma_f32_16x16x32_bf16(a, bw0, vacc[mt][0], 0, 0, 0);
                vacc[mt][1] = __builtin_amdgcn_mfma_f32_16x16x32_bf16(a, bw1, vacc[mt][1], 0, 0, 0);
            }
        }
        // Vt[d][n], 56 tokens, stride 112B (n = mt*16+4hi+r, d = 32wv+16ntl+c)
#pragma unroll
        for (int mt = 0; mt < 4; ++mt)
#pragma unroll
            for (int ntl = 0; ntl < 2; ++ntl) {
                int n0 = mt * 16 + 4 * hi;
                if (n0 < 56) {
                    int d = 32 * wv + ntl * 16 + c;
                    bf16x4 pv;
#pragma unroll
                    for (int r = 0; r < 4; ++r) pv[r] = (bf16_t)vacc[mt][ntl][r];
                    *(bf16x4*)(smem + LDS_VT + d * 112 + n0 * 2) = pv;
                }
            }
    }
    __syncthreads();                             // barrier C: Xw reads done -> P may clobber Xw+Q

    // ---------------- P·V per head; O accumulators stay in regs ----------------
    f32x4 oacc2[2][4];
#pragma unroll
    for (int hl = 0; hl < 2; ++hl) {
        int h = 2 * wv + hl;
        asm volatile("s_waitcnt lgkmcnt(0)" ::: "memory");  // drain prior P reads before overwrite
#pragma unroll
        for (int nt = 0; nt < 4; ++nt)
#pragma unroll
            for (int mt = 0; mt < 4; ++mt) {
                int m = mt * 16 + c;
                if (m < 49) {                    // P region is 49 rows
                    int ch = (8 * wv + 2 * nt + (hi >> 1)) ^ (m & 7);
                    *(bf16x4*)(smem + LDS_P + m * 512 + ch * 16 + (hi & 1) * 8) = pk[hl][nt * 4 + mt];
                }
            }
        f32x4 oacc[4] = {fzero, fzero, fzero, fzero};
#pragma unroll
        for (int ks = 0; ks < 2; ++ks) {
            int rowV = 16 * h + c;
            bf16x8 vb = (ks == 1 && hi == 3) ? zero8()
                      : *(const bf16x8*)(smem + LDS_VT + rowV * 112 + ks * 64 + hi * 16);
#pragma unroll
            for (int mt = 0; mt < 4; ++mt) {
                int rowP = mt * 16 + c;
                int rowPc = (rowP < 49) ? rowP : 48;   // clamp into 49-row P
                int chP = (8 * wv + 4 * ks + hi) ^ (rowPc & 7);
                bf16x8 pa = *(const bf16x8*)(smem + LDS_P + rowPc * 512 + chP * 16);
                oacc[mt] = __builtin_amdgcn_mfma_f32_16x16x32_bf16(pa, vb, oacc[mt], 0, 0, 0);
            }
        }
#pragma unroll
        for (int mt = 0; mt < 4; ++mt) oacc2[hl][mt] = oacc[mt];
    }
    __syncthreads();                             // barrier D: all P reads done, O overlay allowed

    // O (bf16, row-major [64][256B]) at [0,16384)
#pragma unroll
    for (int hl = 0; hl < 2; ++hl)
#pragma unroll
        for (int mt = 0; mt < 4; ++mt)
#pragma unroll
            for (int r = 0; r < 4; ++r) {
                int row = mt * 16 + hi * 4 + r;
                int col = 16 * (2 * wv + hl) + c;
                int ch = (col >> 3) ^ (row & 7);
                *(bf16_t*)(smem + LDS_O + row * 256 + ch * 16 + (col & 7) * 2) = (bf16_t)oacc2[hl][mt][r];
            }
    __syncthreads();                             // barrier E: O complete

    // ---------------- output projection + b_o, scatter to [B,112,112,128] ----------------
    bf16x8 bwo[4][2];
#pragma unroll
    for (int ks = 0; ks < 4; ++ks)
#pragma unroll
        for (int ntl = 0; ntl < 2; ++ntl)
            bwo[ks][ntl] = *(const bf16x8*)(wpack + 3 * 16384 +
                             ((ks * 8 + (2 * wv + ntl)) * 64 + lane) * 8);
    float bb0 = b_o[32 * wv + c];
    float bb1 = b_o[32 * wv + 16 + c];
#pragma unroll
    for (int mt = 0; mt < 4; ++mt) {
        bf16x8 a[4];
#pragma unroll
        for (int ks = 0; ks < 4; ++ks) {
            int row = mt * 16 + c;
            int ch = (4 * ks + hi) ^ (row & 7);
            a[ks] = *(const bf16x8*)(smem + LDS_O + row * 256 + ch * 16);
        }
        f32x4 acc[2] = {fzero, fzero};
#pragma unroll
        for (int ks = 0; ks < 4; ++ks)
#pragma unroll
            for (int ntl = 0; ntl < 2; ++ntl)
                acc[ntl] = __builtin_amdgcn_mfma_f32_16x16x32_bf16(a[ks], bwo[ks][ntl], acc[ntl], 0, 0, 0);
#pragma unroll
        for (int ntl = 0; ntl < 2; ++ntl)
#pragma unroll
            for (int r = 0; r < 4; ++r) {
                int m = mt * 16 + hi * 4 + r;
                if (m < 49) {
                    int i = m / 7, j = m % 7;
                    out[((b * 112 + wh * 7 + i) * 112 + ww * 7 + j) * 128 + 32 * wv + ntl * 16 + c]
                        = acc[ntl][r] + (ntl == 0 ? bb0 : bb1);
                }
            }
    }
}

extern "C" void kernel_launch(void* const* d_in, const int* in_sizes, int n_in,
                              void* d_out, int out_size, void* d_ws, size_t ws_size,
                              hipStream_t stream) {
    const float* x   = (const float*)d_in[0];
    const float* wq  = (const float*)d_in[1];
    const float* wk  = (const float*)d_in[2];
    const float* wvp = (const float*)d_in[3];
    const float* wo  = (const float*)d_in[4];
    const float* bo  = (const float*)d_in[5];
    const float* rb  = (const float*)d_in[6];
    bf16_t* wpack = (bf16_t*)d_ws;               // needs 196608 bytes of ws

    repack_kernel<<<384, 256, 0, stream>>>(wq, wk, wvp, wo, rb, wpack);
    win_attn_kernel<<<4096, 256, 0, stream>>>(x, bo, wpack, (float*)d_out);
}

// Round 6
// 132.501 us; speedup vs baseline: 1.1143x; 1.1143x over previous
//
#include <hip/hip_runtime.h>

typedef __bf16 bf16_t;
typedef __attribute__((ext_vector_type(8))) __bf16 bf16x8;
typedef __attribute__((ext_vector_type(4))) __bf16 bf16x4;
typedef __attribute__((ext_vector_type(4))) float f32x4;
typedef __attribute__((ext_vector_type(4))) short short4v;

#if __has_builtin(__builtin_amdgcn_mfma_f32_16x16x16bf16_1k)
#define HAVE_MFMA16 1
#else
#define HAVE_MFMA16 0
#endif

// LDS layout (bytes), 37632 total (+256 runtime -> 40960 @8K granule -> 4 blocks/CU):
//   Xw [49 rows][256B] at [0,12544)      } dead after projections -> O [49][256B] overlays it
//   Q  [49 rows][256B] at [12544,25088)  } read only by QK^T (wave-private cols)
//   K  [49 rows][256B] at [25088,37632)  } read only by QK^T (wave-private cols)
// P and V never touch LDS: pk[] is bit-exactly the 16x16x16 A-frag, and the
// V-projection C-output packed to bf16x4 is bit-exactly the 16x16x16 B-frag.
// Rows >=49 never stored; reads clamp row->48 (garbage masked by bias=-1e4 on
// keys n>=49 and the m<49 output-store guard).
#define LDS_XW 0
#define LDS_Q  12544
#define LDS_K  25088
#define LDS_O  0

// ws layout (bf16 elements): wq_pack[16384] wk_pack[16384] wv_pack[16384] wo_pack[16384]
// biasPad[8*64*64]  => 98304 elements = 196608 bytes

__device__ __forceinline__ bf16x8 zero8() {
    bf16x8 v;
#pragma unroll
    for (int i = 0; i < 8; ++i) v[i] = (bf16_t)0.0f;
    return v;
}

#if HAVE_MFMA16
__device__ __forceinline__ f32x4 mfma16(bf16x4 a, bf16x4 b, f32x4 c) {
    return __builtin_amdgcn_mfma_f32_16x16x16bf16_1k(
        __builtin_bit_cast(short4v, a), __builtin_bit_cast(short4v, b), c, 0, 0, 0);
}
#endif

__global__ void repack_kernel(const float* __restrict__ wq, const float* __restrict__ wk,
                              const float* __restrict__ wv, const float* __restrict__ wo,
                              const float* __restrict__ rel_bias, bf16_t* __restrict__ ws)
{
    int idx = blockIdx.x * 256 + threadIdx.x;
    if (idx < 65536) {
        // B-fragment order for mfma_f32_16x16x32_bf16:
        // pack[(((ks*8 + nt)*64 + lane)*8 + j)] = W[ks*32 + (lane>>4)*8 + j][nt*16 + (lane&15)]
        int mat = idx >> 14;
        int r = idx & 16383;
        int j = r & 7, l = (r >> 3) & 63, nt = (r >> 9) & 7, ks = r >> 12;
        int k = ks * 32 + (l >> 4) * 8 + j;
        int n = nt * 16 + (l & 15);
        const float* w = (mat == 0) ? wq : (mat == 1) ? wk : (mat == 2) ? wv : wo;
        float v = w[k * 128 + n];
        if (mat == 0) v *= 0.25f;            // fold q scale HS^-0.5
        ws[idx] = (bf16_t)v;
    } else if (idx < 98304) {
        // biasPad[h][m][n], padding (m>=49 or n>=49) = -1e4 (doubles as softmax mask)
        int r = idx - 65536;
        int h = r >> 12, m = (r >> 6) & 63, n = r & 63;
        float v = -10000.0f;
        if (m < 49 && n < 49) {
            int im = m / 7, jm = m % 7, in_ = n / 7, jn = n % 7;
            v = rel_bias[((im - in_ + 6) * 13 + (jm - jn + 6)) * 8 + h];
        }
        ws[idx] = (bf16_t)v;
    }
}

__global__ __launch_bounds__(256, 2)
void win_attn_kernel(const float* __restrict__ x, const float* __restrict__ b_o,
                     const bf16_t* __restrict__ wpack, float* __restrict__ out)
{
    __shared__ __align__(16) unsigned char smem[37632];
    const bf16_t* biasT = wpack + 65536;
    const int tid = threadIdx.x;
    const int blk = blockIdx.x;                  // 4096 windows: b*256 + wh*16 + ww
    const int b  = blk >> 8;
    const int wh = (blk >> 4) & 15;
    const int ww = blk & 15;
    const int wv = tid >> 6;                     // wave 0..3, owns heads {2wv,2wv+1}, cols [32wv,32wv+32)
    const int lane = tid & 63;
    const int c  = lane & 15;
    const int hi = lane >> 4;                    // 0..3
    const f32x4 fzero = {0.f, 0.f, 0.f, 0.f};

    // ---------------- stage x window -> Xw [49][128] bf16 ----------------
#pragma unroll
    for (int it = 0; it < 7; ++it) {
        int idx = tid + it * 256;                // need 1568 = 49 rows * 32 float4
        if (idx < 1568) {
            int m  = idx >> 5;                   // 0..48
            int c4 = idx & 31;
            int i = m / 7, j = m - 7 * i;
            float4 v = *(const float4*)(x + ((b * 112 + wh * 7 + i) * 112 + ww * 7 + j) * 128 + c4 * 4);
            bf16x4 bv;
            bv[0] = (bf16_t)v.x; bv[1] = (bf16_t)v.y; bv[2] = (bf16_t)v.z; bv[3] = (bf16_t)v.w;
            int ch = (c4 >> 1) ^ (m & 7);        // 16B-chunk XOR swizzle
            *(bf16x4*)(smem + LDS_XW + m * 256 + ch * 16 + (c4 & 1) * 8) = bv;
        }
    }
    __syncthreads();                             // barrier A: Xw ready

    // ---------------- projections: Q, K -> LDS (row-major); V -> regs (B-frag) ----------------
    bf16x4 vreg[4][2];                           // V[token = mt*16+4hi+r][d = 32wv+16ntl+c]
#pragma unroll
    for (int mat = 0; mat < 3; ++mat) {
        bf16x8 bw[4][2];
#pragma unroll
        for (int ks = 0; ks < 4; ++ks)
#pragma unroll
            for (int ntl = 0; ntl < 2; ++ntl)
                bw[ks][ntl] = *(const bf16x8*)(wpack + mat * 16384 +
                                 ((ks * 8 + (2 * wv + ntl)) * 64 + lane) * 8);
#pragma unroll
        for (int mt = 0; mt < 4; ++mt) {
            int row = mt * 16 + c;
            int rowc = (row < 49) ? row : 48;    // clamp: rows >=49 read row 48 (finite dup)
            bf16x8 a[4];
#pragma unroll
            for (int ks = 0; ks < 4; ++ks) {
                int ch = (4 * ks + hi) ^ (rowc & 7);
                a[ks] = *(const bf16x8*)(smem + LDS_XW + rowc * 256 + ch * 16);
            }
            f32x4 acc[2] = {fzero, fzero};
#pragma unroll
            for (int ks = 0; ks < 4; ++ks)
#pragma unroll
                for (int ntl = 0; ntl < 2; ++ntl)
                    acc[ntl] = __builtin_amdgcn_mfma_f32_16x16x32_bf16(a[ks], bw[ks][ntl], acc[ntl], 0, 0, 0);
            // C layout: col = lane&15, row = 4*hi + reg
#pragma unroll
            for (int ntl = 0; ntl < 2; ++ntl) {
                if (mat < 2) {
#pragma unroll
                    for (int r = 0; r < 4; ++r) {
                        int orow = mt * 16 + hi * 4 + r;
                        if (orow < 49) {
                            int col = 32 * wv + ntl * 16 + c;
                            int ch = (col >> 3) ^ (orow & 7);
                            *(bf16_t*)(smem + (mat == 0 ? LDS_Q : LDS_K) + orow * 256 + ch * 16 + (col & 7) * 2)
                                = (bf16_t)acc[ntl][r];
                        }
                    }
                } else {                          // V stays in registers as PV B-frag
#pragma unroll
                    for (int r = 0; r < 4; ++r) vreg[mt][ntl][r] = (bf16_t)acc[ntl][r];
                }
            }
        }
    }
    // no barrier: each wave's QK^T reads only its own 32 channel-columns of Q/K

    // ---------------- S^T = K·Q^T (+bias) -> softmax over n -> pack P in regs ----------------
    bf16x4 pk[2][16];
#pragma unroll
    for (int hl = 0; hl < 2; ++hl) {
        int h = 2 * wv + hl;
#if HAVE_MFMA16
        bf16x4 ka[4];                            // K[n = t*16+c][ch = 16h + 4hi + j]
#pragma unroll
        for (int t = 0; t < 4; ++t) {
            int row = t * 16 + c;
            int rowc = (row < 49) ? row : 48;
            int ch = (2 * h + (hi >> 1)) ^ (rowc & 7);
            ka[t] = *(const bf16x4*)(smem + LDS_K + rowc * 256 + ch * 16 + (hi & 1) * 8);
        }
#else
        bf16x8 ka[4];
#pragma unroll
        for (int t = 0; t < 4; ++t) {
            int row = t * 16 + c;
            int rowc = (row < 49) ? row : 48;
            if (hi < 2) {                        // HS=16: k=16..31 lanes supply zeros
                int ch = (4 * wv + 2 * hl + hi) ^ (rowc & 7);
                ka[t] = *(const bf16x8*)(smem + LDS_K + rowc * 256 + ch * 16);
            } else {
                ka[t] = zero8();
            }
        }
#endif
#pragma unroll
        for (int mt = 0; mt < 4; ++mt) {         // per-mt: only st[4] live (low VGPR)
            int row = mt * 16 + c;
            int rowc = (row < 49) ? row : 48;
            f32x4 st[4];                         // S^T slice; col=m=c, row=n=nt*16+4hi+r
#if HAVE_MFMA16
            bf16x4 qb;
            {
                int ch = (2 * h + (hi >> 1)) ^ (rowc & 7);
                qb = *(const bf16x4*)(smem + LDS_Q + rowc * 256 + ch * 16 + (hi & 1) * 8);
            }
#pragma unroll
            for (int nt = 0; nt < 4; ++nt)
                st[nt] = mfma16(ka[nt], qb, fzero);
#else
            bf16x8 qb;
            if (hi < 2) {
                int ch = (4 * wv + 2 * hl + hi) ^ (rowc & 7);
                qb = *(const bf16x8*)(smem + LDS_Q + rowc * 256 + ch * 16);
            } else {
                qb = zero8();
            }
#pragma unroll
            for (int nt = 0; nt < 4; ++nt)
                st[nt] = __builtin_amdgcn_mfma_f32_16x16x32_bf16(ka[nt], qb, fzero, 0, 0, 0);
#endif
#pragma unroll
            for (int nt = 0; nt < 4; ++nt) {
                int m = mt * 16 + c;
                bf16x4 bb = *(const bf16x4*)(biasT + (h * 64 + m) * 64 + nt * 16 + 4 * hi);
#pragma unroll
                for (int r = 0; r < 4; ++r)
                    st[nt][r] += (float)bb[r];
            }
            float mx = -3.0e30f;
#pragma unroll
            for (int nt = 0; nt < 4; ++nt)
#pragma unroll
                for (int r = 0; r < 4; ++r) mx = fmaxf(mx, st[nt][r]);
            mx = fmaxf(mx, __shfl_xor(mx, 16));
            mx = fmaxf(mx, __shfl_xor(mx, 32));
            float sum = 0.f;
#pragma unroll
            for (int nt = 0; nt < 4; ++nt)
#pragma unroll
                for (int r = 0; r < 4; ++r) {
                    float p = __expf(st[nt][r] - mx);
                    st[nt][r] = p;
                    sum += p;
                }
            sum += __shfl_xor(sum, 16);
            sum += __shfl_xor(sum, 32);
            float inv = 1.f / sum;
#pragma unroll
            for (int nt = 0; nt < 4; ++nt) {
                bf16x4 pv;
#pragma unroll
                for (int r = 0; r < 4; ++r) pv[r] = (bf16_t)(st[nt][r] * inv);
                pk[hl][nt * 4 + mt] = pv;        // P[m=mt*16+c][n=nt*16+4hi+r] == 16x16x16 A-frag
            }
        }
    }
    __syncthreads();                             // barrier B: Xw reads done everywhere -> O may overlay Xw

    // ---------------- P·V per head, pure registers; O -> LDS over Xw ----------------
#pragma unroll
    for (int hl = 0; hl < 2; ++hl) {
        int h = 2 * wv + hl;
        f32x4 oacc[4];
#pragma unroll
        for (int mt = 0; mt < 4; ++mt) oacc[mt] = fzero;
#if HAVE_MFMA16
#pragma unroll
        for (int nt = 0; nt < 4; ++nt)
#pragma unroll
            for (int mt = 0; mt < 4; ++mt)
                oacc[mt] = mfma16(pk[hl][nt * 4 + mt], vreg[nt][hl], oacc[mt]);
#else
        // build K=32 B-frags from vreg via in-wave shuffles (4-lane hi-group transpose)
#pragma unroll
        for (int ks = 0; ks < 2; ++ks) {
            uint2 u2a[2], u2b[2];
            u2a[0] = __builtin_bit_cast(uint2, vreg[2 * ks][hl]);
            u2b[0] = __builtin_bit_cast(uint2, vreg[2 * ks + 1][hl]);
            int s0 = c + 32 * (hi & 1);
            uint2 lo_a, lo_b, hi_a, hi_b;
            lo_a.x = __shfl((int)u2a[0].x, s0); lo_a.y = __shfl((int)u2a[0].y, s0);
            lo_b.x = __shfl((int)u2b[0].x, s0); lo_b.y = __shfl((int)u2b[0].y, s0);
            hi_a.x = __shfl((int)u2a[0].x, s0 + 16); hi_a.y = __shfl((int)u2a[0].y, s0 + 16);
            hi_b.x = __shfl((int)u2b[0].x, s0 + 16); hi_b.y = __shfl((int)u2b[0].y, s0 + 16);
            uint2 lo = (hi >> 1) ? lo_b : lo_a;
            uint2 hh = (hi >> 1) ? hi_b : hi_a;
            bf16x8 vb;
            *(uint2*)&vb = lo;
            *((uint2*)&vb + 1) = hh;
#pragma unroll
            for (int mt = 0; mt < 4; ++mt) {
                bf16x8 pa;
                *(bf16x4*)&pa = pk[hl][(2 * ks) * 4 + mt];
                *((bf16x4*)&pa + 1) = pk[hl][(2 * ks + 1) * 4 + mt];
                oacc[mt] = __builtin_amdgcn_mfma_f32_16x16x32_bf16(pa, vb, oacc[mt], 0, 0, 0);
            }
        }
#endif
        // O (bf16, [49][256B]) overlays Xw; col = 16h + c, row = mt*16+4hi+r
#pragma unroll
        for (int mt = 0; mt < 4; ++mt)
#pragma unroll
            for (int r = 0; r < 4; ++r) {
                int row = mt * 16 + hi * 4 + r;
                if (row < 49) {
                    int col = 16 * h + c;
                    int ch = (col >> 3) ^ (row & 7);
                    *(bf16_t*)(smem + LDS_O + row * 256 + ch * 16 + (col & 7) * 2) = (bf16_t)oacc[mt][r];
                }
            }
    }
    __syncthreads();                             // barrier C: O complete from all waves

    // ---------------- output projection + b_o, scatter to [B,112,112,128] ----------------
    bf16x8 bwo[4][2];
#pragma unroll
    for (int ks = 0; ks < 4; ++ks)
#pragma unroll
        for (int ntl = 0; ntl < 2; ++ntl)
            bwo[ks][ntl] = *(const bf16x8*)(wpack + 3 * 16384 +
                             ((ks * 8 + (2 * wv + ntl)) * 64 + lane) * 8);
    float bb0 = b_o[32 * wv + c];
    float bb1 = b_o[32 * wv + 16 + c];
#pragma unroll
    for (int mt = 0; mt < 4; ++mt) {
        int row = mt * 16 + c;
        int rowc = (row < 49) ? row : 48;        // clamp into 49-row O
        bf16x8 a[4];
#pragma unroll
        for (int ks = 0; ks < 4; ++ks) {
            int ch = (4 * ks + hi) ^ (rowc & 7);
            a[ks] = *(const bf16x8*)(smem + LDS_O + rowc * 256 + ch * 16);
        }
        f32x4 acc[2] = {fzero, fzero};
#pragma unroll
        for (int ks = 0; ks < 4; ++ks)
#pragma unroll
            for (int ntl = 0; ntl < 2; ++ntl)
                acc[ntl] = __builtin_amdgcn_mfma_f32_16x16x32_bf16(a[ks], bwo[ks][ntl], acc[ntl], 0, 0, 0);
#pragma unroll
        for (int ntl = 0; ntl < 2; ++ntl)
#pragma unroll
            for (int r = 0; r < 4; ++r) {
                int m = mt * 16 + hi * 4 + r;
                if (m < 49) {
                    int i = m / 7, j = m % 7;
                    out[((b * 112 + wh * 7 + i) * 112 + ww * 7 + j) * 128 + 32 * wv + ntl * 16 + c]
                        = acc[ntl][r] + (ntl == 0 ? bb0 : bb1);
                }
            }
    }
}

extern "C" void kernel_launch(void* const* d_in, const int* in_sizes, int n_in,
                              void* d_out, int out_size, void* d_ws, size_t ws_size,
                              hipStream_t stream) {
    const float* x   = (const float*)d_in[0];
    const float* wq  = (const float*)d_in[1];
    const float* wk  = (const float*)d_in[2];
    const float* wvp = (const float*)d_in[3];
    const float* wo  = (const float*)d_in[4];
    const float* bo  = (const float*)d_in[5];
    const float* rb  = (const float*)d_in[6];
    bf16_t* wpack = (bf16_t*)d_ws;               // needs 196608 bytes of ws

    repack_kernel<<<384, 256, 0, stream>>>(wq, wk, wvp, wo, rb, wpack);
    win_attn_kernel<<<4096, 256, 0, stream>>>(x, bo, wpack, (float*)d_out);
}